// Round 1
// baseline (469.370 us; speedup 1.0000x reference)
//
#include <hip/hip_runtime.h>
#include <cstddef>

#define NB 8
#define NT 2048
#define NE 256
#define NH 4
#define ND 64
#define NP 8

// ---------------- prep: u = w_bd @ w_o ; uv_h = u_h @ w_v slice ; consts ; zero psum ----
__global__ __launch_bounds__(256) void prep_kernel(
    const float* __restrict__ w_o, const float* __restrict__ b_o,
    const float* __restrict__ w_bd, const float* __restrict__ b_bd,
    const float* __restrict__ w_v, const float* __restrict__ b_v,
    float* __restrict__ uv, float* __restrict__ consts, float* __restrict__ psum)
{
  __shared__ float wbd_s[NE];
  __shared__ float u_s[NE];
  const int tid = threadIdx.x;
  wbd_s[tid] = w_bd[tid];
  __syncthreads();
  float a = 0.f;
  for (int j = 0; j < NE; ++j) a = fmaf(wbd_s[j], w_o[j * NE + tid], a);
  u_s[tid] = a;
  __syncthreads();
  #pragma unroll
  for (int hh = 0; hh < NH; ++hh) {
    float a2 = 0.f;
    for (int d = 0; d < ND; ++d)
      a2 = fmaf(u_s[hh * ND + d], w_v[(size_t)(hh * ND + d) * NE + tid], a2);
    uv[hh * NE + tid] = a2;
  }
  if (tid == 0) {
    float cc = 0.f;
    for (int j = 0; j < NE; ++j) cc = fmaf(wbd_s[j], b_o[j], cc);
    consts[0] = cc + b_bd[0];
  }
  if (tid >= 4 && tid < 8) {
    const int hh = tid - 4;
    float cv = 0.f;
    for (int d = 0; d < ND; ++d) cv = fmaf(u_s[hh * ND + d], b_v[hh * ND + d], cv);
    consts[1 + hh] = cv;
  }
  for (int i = tid; i < NB * NP * NE; i += 256) psum[i] = 0.f;
}

// ---------------- generic f32 GEMM: C = A[M,256] @ W[N,256]^T + bias ----------------
// BM=128 BN=64 BK=32, 256 threads, 8x4 per-thread tile.
// mode 0: C[row*256+n]; mode 1: head layout C[((b*NH+head)*NT+t)*ND+d]
__global__ __launch_bounds__(256) void gemm_kernel(
    const float* __restrict__ A, const float* __restrict__ W,
    const float* __restrict__ bias, float* __restrict__ C, int mode)
{
  __shared__ float a_s[32][132];
  __shared__ float b_s[32][68];
  const int tid = threadIdx.x;
  const int m0 = blockIdx.x * 128;
  const int n0 = blockIdx.y * 64;
  const int tm = tid >> 4, tn = tid & 15;
  const int r0 = tm * 8, c0 = tn * 4;
  float acc[8][4] = {};
  for (int k0 = 0; k0 < NE; k0 += 32) {
    #pragma unroll
    for (int i = 0; i < 4; ++i) {
      const int idx = i * 256 + tid;
      const int row = idx >> 3, kq = idx & 7;
      const float4 v = *(const float4*)(A + (size_t)(m0 + row) * NE + k0 + kq * 4);
      a_s[kq * 4 + 0][row] = v.x; a_s[kq * 4 + 1][row] = v.y;
      a_s[kq * 4 + 2][row] = v.z; a_s[kq * 4 + 3][row] = v.w;
    }
    #pragma unroll
    for (int i = 0; i < 2; ++i) {
      const int idx = i * 256 + tid;
      const int row = idx >> 3, kq = idx & 7;
      const float4 v = *(const float4*)(W + (size_t)(n0 + row) * NE + k0 + kq * 4);
      b_s[kq * 4 + 0][row] = v.x; b_s[kq * 4 + 1][row] = v.y;
      b_s[kq * 4 + 2][row] = v.z; b_s[kq * 4 + 3][row] = v.w;
    }
    __syncthreads();
    #pragma unroll 8
    for (int kk = 0; kk < 32; ++kk) {
      const float4 a0 = *(const float4*)&a_s[kk][r0];
      const float4 a1 = *(const float4*)&a_s[kk][r0 + 4];
      const float4 bv = *(const float4*)&b_s[kk][c0];
      const float av[8] = {a0.x, a0.y, a0.z, a0.w, a1.x, a1.y, a1.z, a1.w};
      const float bb[4] = {bv.x, bv.y, bv.z, bv.w};
      #pragma unroll
      for (int i = 0; i < 8; ++i)
        #pragma unroll
        for (int j = 0; j < 4; ++j)
          acc[i][j] = fmaf(av[i], bb[j], acc[i][j]);
    }
    __syncthreads();
  }
  #pragma unroll
  for (int i = 0; i < 8; ++i) {
    const int row = m0 + r0 + i;
    #pragma unroll
    for (int j = 0; j < 4; ++j) {
      const int n = n0 + c0 + j;
      const float v = acc[i][j] + bias[n];
      if (mode == 0) {
        C[(size_t)row * NE + n] = v;
      } else {
        const int head = n >> 6, d = n & 63;
        const int b = row >> 11, t = row & 2047;
        C[(((size_t)(b * NH + head)) * NT + t) * ND + d] = v;
      }
    }
  }
}

// ---------------- vu[b,h,t] = h_row . uv_h + cv_h (one wave per token) ----------------
__global__ __launch_bounds__(256) void vu_kernel(
    const float* __restrict__ h, const float* __restrict__ uv,
    const float* __restrict__ consts, float* __restrict__ vuout)
{
  __shared__ float uv_s[NH][NE];
  const int tid = threadIdx.x;
  #pragma unroll
  for (int i = 0; i < 4; ++i) { const int idx = i * 256 + tid; uv_s[idx >> 8][idx & 255] = uv[idx]; }
  __syncthreads();
  const int wave = tid >> 6, lane = tid & 63;
  const int token = blockIdx.x * 4 + wave;            // = b*NT + t
  const float4 hv = *(const float4*)(h + (size_t)token * NE + lane * 4);
  const int b = token >> 11, t = token & 2047;
  #pragma unroll
  for (int hh = 0; hh < NH; ++hh) {
    float p = hv.x * uv_s[hh][lane * 4 + 0] + hv.y * uv_s[hh][lane * 4 + 1]
            + hv.z * uv_s[hh][lane * 4 + 2] + hv.w * uv_s[hh][lane * 4 + 3];
    #pragma unroll
    for (int off = 32; off > 0; off >>= 1) p += __shfl_down(p, off);
    if (lane == 0) vuout[((size_t)(b * NH + hh)) * NT + t] = p + consts[1 + hh];
  }
}

// ---------------- attention, reduced: sp[b,t,h] = softmax(q.k/8) . vu ----------------
// Q-tile 128 rows (staged once), K-tile 64, 256 threads, 4x8 per-thread score tile.
__global__ __launch_bounds__(256) void attn_kernel(
    const float* __restrict__ q, const float* __restrict__ k,
    const float* __restrict__ vu, float* __restrict__ sp)
{
  __shared__ float q_s[64][128];   // [d][m]
  __shared__ float k_s[64][64];    // [d][n]
  __shared__ float vu_s[64];
  const int tid = threadIdx.x;
  const int bh = blockIdx.y;
  const int b = bh >> 2, hh = bh & 3;
  const float* qb = q + (size_t)bh * NT * ND;
  const float* kb = k + (size_t)bh * NT * ND;
  const float* vub = vu + (size_t)bh * NT;
  const int qt0 = blockIdx.x * 128;
  #pragma unroll
  for (int i = 0; i < 8; ++i) {
    const int idx = i * 256 + tid;
    const int row = idx >> 4, dq = idx & 15;
    const float4 v = *(const float4*)(qb + (size_t)(qt0 + row) * ND + dq * 4);
    q_s[dq * 4 + 0][row] = v.x; q_s[dq * 4 + 1][row] = v.y;
    q_s[dq * 4 + 2][row] = v.z; q_s[dq * 4 + 3][row] = v.w;
  }
  const int rg = tid >> 3, cg = tid & 7;
  const int r0 = rg * 4, c0 = cg * 8;
  float m[4], l[4], s[4];
  #pragma unroll
  for (int i = 0; i < 4; ++i) { m[i] = -1e30f; l[i] = 0.f; s[i] = 0.f; }
  for (int kt = 0; kt < 32; ++kt) {
    __syncthreads();
    #pragma unroll
    for (int i = 0; i < 4; ++i) {
      const int idx = i * 256 + tid;
      const int row = idx >> 4, dq = idx & 15;
      const float4 v = *(const float4*)(kb + (size_t)(kt * 64 + row) * ND + dq * 4);
      k_s[dq * 4 + 0][row] = v.x; k_s[dq * 4 + 1][row] = v.y;
      k_s[dq * 4 + 2][row] = v.z; k_s[dq * 4 + 3][row] = v.w;
    }
    if (tid < 64) vu_s[tid] = vub[kt * 64 + tid];
    __syncthreads();
    float acc[4][8] = {};
    #pragma unroll 4
    for (int d = 0; d < 64; ++d) {
      const float4 qv = *(const float4*)&q_s[d][r0];
      const float4 k0v = *(const float4*)&k_s[d][c0];
      const float4 k1v = *(const float4*)&k_s[d][c0 + 4];
      const float av[4] = {qv.x, qv.y, qv.z, qv.w};
      const float bb[8] = {k0v.x, k0v.y, k0v.z, k0v.w, k1v.x, k1v.y, k1v.z, k1v.w};
      #pragma unroll
      for (int i = 0; i < 4; ++i)
        #pragma unroll
        for (int j = 0; j < 8; ++j)
          acc[i][j] = fmaf(av[i], bb[j], acc[i][j]);
    }
    #pragma unroll
    for (int i = 0; i < 4; ++i) {
      float mx = acc[i][0];
      #pragma unroll
      for (int j = 1; j < 8; ++j) mx = fmaxf(mx, acc[i][j]);
      mx *= 0.125f;                       // exact (power of 2)
      mx = fmaxf(mx, __shfl_xor(mx, 1, 8));
      mx = fmaxf(mx, __shfl_xor(mx, 2, 8));
      mx = fmaxf(mx, __shfl_xor(mx, 4, 8));
      const float mn = fmaxf(m[i], mx);
      const float al = __expf(m[i] - mn);
      float es = 0.f, ev = 0.f;
      #pragma unroll
      for (int j = 0; j < 8; ++j) {
        const float e = __expf(fmaf(acc[i][j], 0.125f, -mn));
        es += e;
        ev = fmaf(e, vu_s[c0 + j], ev);
      }
      es += __shfl_xor(es, 1, 8); ev += __shfl_xor(ev, 1, 8);
      es += __shfl_xor(es, 2, 8); ev += __shfl_xor(ev, 2, 8);
      es += __shfl_xor(es, 4, 8); ev += __shfl_xor(ev, 4, 8);
      l[i] = fmaf(l[i], al, es);
      s[i] = fmaf(s[i], al, ev);
      m[i] = mn;
    }
  }
  if (cg == 0) {
    #pragma unroll
    for (int i = 0; i < 4; ++i)
      sp[((size_t)b * NT + qt0 + r0 + i) * NH + hh] = s[i] / l[i];
  }
}

// ---------------- boundary: sigmoid, cumsum, pid, counts (one block per batch) --------
__global__ __launch_bounds__(256) void boundary_kernel(
    const float* __restrict__ sp, const float* __restrict__ consts,
    int* __restrict__ pid, int* __restrict__ counts)
{
  const int b = blockIdx.x, tid = threadIdx.x;
  __shared__ float partial[256];
  __shared__ int cnt_s[8];
  const float c = consts[0];
  float v[8];
  float run = 0.f;
  #pragma unroll
  for (int i = 0; i < 8; ++i) {
    const int t = tid * 8 + i;
    const float* p = sp + ((size_t)b * NT + t) * NH;
    const float logit = p[0] + p[1] + p[2] + p[3] + c;
    const float bs = 1.f / (1.f + expf(-logit));
    run += bs;
    v[i] = run;
  }
  float x = run;
  partial[tid] = x;
  __syncthreads();
  for (int off = 1; off < 256; off <<= 1) {
    const float y = (tid >= off) ? partial[tid - off] : 0.f;
    __syncthreads();
    x += y;
    partial[tid] = x;
    __syncthreads();
  }
  const float total = partial[255];
  if (tid < 8) cnt_s[tid] = 0;
  __syncthreads();
  const float denom = fmaxf(total, 1e-6f);
  const float excl = x - run;
  #pragma unroll
  for (int i = 0; i < 8; ++i) {
    const float norm = (excl + v[i]) / denom;
    int pp = (int)(norm * 8.f);
    pp = pp > 7 ? 7 : pp;
    pid[b * NT + tid * 8 + i] = pp;
    atomicAdd(&cnt_s[pp], 1);
  }
  __syncthreads();
  if (tid < 8) counts[b * 8 + tid] = cnt_s[tid];
}

// ---------------- pool h into patch sums (branchless 8-way select) --------------------
__global__ __launch_bounds__(256) void pool_kernel(
    const float* __restrict__ h, const int* __restrict__ pid, float* __restrict__ psum)
{
  const int b = blockIdx.x >> 3, chunk = blockIdx.x & 7;
  const int tid = threadIdx.x;
  __shared__ int pid_s[256];
  const int t0 = chunk * 256;
  pid_s[tid] = pid[b * NT + t0 + tid];
  __syncthreads();
  float acc[8] = {};
  for (int tok = 0; tok < 256; ++tok) {
    const float val = h[((size_t)b * NT + t0 + tok) * NE + tid];
    const int p = pid_s[tok];
    #pragma unroll
    for (int pp = 0; pp < 8; ++pp) acc[pp] += (p == pp) ? val : 0.f;
  }
  #pragma unroll
  for (int pp = 0; pp < 8; ++pp)
    atomicAdd(&psum[((size_t)b * NP + pp) * NE + tid], acc[pp]);
}

// ---------------- final: out = (psum/count) @ w_pr^T + b_pr --------------------------
__global__ __launch_bounds__(256) void final_kernel(
    const float* __restrict__ psum, const int* __restrict__ counts,
    const float* __restrict__ w_pr, const float* __restrict__ b_pr, float* __restrict__ out)
{
  const int bp = blockIdx.x;
  const int tid = threadIdx.x;
  __shared__ float pe[NE];
  const float cnt = fmaxf((float)counts[bp], 1.f);
  pe[tid] = psum[(size_t)bp * NE + tid] / cnt;
  __syncthreads();
  float acc = 0.f;
  for (int e = 0; e < NE; ++e) acc = fmaf(pe[e], w_pr[(size_t)tid * NE + e], acc);
  out[(size_t)bp * NE + tid] = acc + b_pr[tid];
}

extern "C" void kernel_launch(void* const* d_in, const int* in_sizes, int n_in,
                              void* d_out, int out_size, void* d_ws, size_t ws_size,
                              hipStream_t stream) {
  (void)in_sizes; (void)n_in; (void)out_size; (void)ws_size;
  const float* x    = (const float*)d_in[0];
  const float* w_in = (const float*)d_in[1];
  const float* b_in = (const float*)d_in[2];
  const float* w_q  = (const float*)d_in[3];
  const float* b_q  = (const float*)d_in[4];
  const float* w_k  = (const float*)d_in[5];
  const float* b_k  = (const float*)d_in[6];
  const float* w_v  = (const float*)d_in[7];
  const float* b_v  = (const float*)d_in[8];
  const float* w_o  = (const float*)d_in[9];
  const float* b_o  = (const float*)d_in[10];
  const float* w_bd = (const float*)d_in[11];
  const float* b_bd = (const float*)d_in[12];
  const float* w_pr = (const float*)d_in[13];
  const float* b_pr = (const float*)d_in[14];
  float* out = (float*)d_out;
  float* ws = (float*)d_ws;

  float* hbuf   = ws;                                   // 16384*256
  float* qbuf   = hbuf + (size_t)16384 * 256;           // 4194304
  float* kbuf   = qbuf + (size_t)4194304;               // 4194304
  float* vubuf  = kbuf + (size_t)4194304;               // 65536 [B,H,T]
  float* spbuf  = vubuf + 65536;                        // 65536 [B,T,H]
  float* uvbuf  = spbuf + 65536;                        // 1024
  float* consts = uvbuf + 1024;                         // 8
  float* psum   = consts + 8;                           // 16384
  int*   pid    = (int*)(psum + 16384);                 // 16384
  int*   counts = pid + 16384;                          // 64

  prep_kernel<<<1, 256, 0, stream>>>(w_o, b_o, w_bd, b_bd, w_v, b_v, uvbuf, consts, psum);
  gemm_kernel<<<dim3(128, 4), 256, 0, stream>>>(x, w_in, b_in, hbuf, 0);
  gemm_kernel<<<dim3(128, 4), 256, 0, stream>>>(hbuf, w_q, b_q, qbuf, 1);
  gemm_kernel<<<dim3(128, 4), 256, 0, stream>>>(hbuf, w_k, b_k, kbuf, 1);
  vu_kernel<<<4096, 256, 0, stream>>>(hbuf, uvbuf, consts, vubuf);
  attn_kernel<<<dim3(16, 32), 256, 0, stream>>>(qbuf, kbuf, vubuf, spbuf);
  boundary_kernel<<<8, 256, 0, stream>>>(spbuf, consts, pid, counts);
  pool_kernel<<<64, 256, 0, stream>>>(hbuf, pid, psum);
  final_kernel<<<64, 256, 0, stream>>>(psum, counts, w_pr, b_pr, out);
}

// Round 2
// 314.294 us; speedup vs baseline: 1.4934x; 1.4934x over previous
//
#include <hip/hip_runtime.h>
#include <cstddef>

#define NB 8
#define NT 2048
#define NE 256
#define NH 4
#define ND 64
#define NP 8

typedef short bf16x8 __attribute__((ext_vector_type(8)));
typedef float f32x4 __attribute__((ext_vector_type(4)));

__device__ __forceinline__ unsigned short f2bf(float f) {
  unsigned u = __builtin_bit_cast(unsigned, f);
  u += 0x7fffu + ((u >> 16) & 1u);          // RNE
  return (unsigned short)(u >> 16);
}
__device__ __forceinline__ float bf2f(unsigned short h) {
  unsigned u = ((unsigned)h) << 16;
  return __builtin_bit_cast(float, u);
}

// ---------------- prep: u = w_bd @ w_o ; uv_h = u_h @ w_v slice ; consts ; zero psum ----
__global__ __launch_bounds__(256) void prep_kernel(
    const float* __restrict__ w_o, const float* __restrict__ b_o,
    const float* __restrict__ w_bd, const float* __restrict__ b_bd,
    const float* __restrict__ w_v, const float* __restrict__ b_v,
    float* __restrict__ uv, float* __restrict__ consts, float* __restrict__ psum)
{
  __shared__ float wbd_s[NE];
  __shared__ float u_s[NE];
  const int tid = threadIdx.x;
  wbd_s[tid] = w_bd[tid];
  __syncthreads();
  float a = 0.f;
  for (int j = 0; j < NE; ++j) a = fmaf(wbd_s[j], w_o[j * NE + tid], a);
  u_s[tid] = a;
  __syncthreads();
  #pragma unroll
  for (int hh = 0; hh < NH; ++hh) {
    float a2 = 0.f;
    for (int d = 0; d < ND; ++d)
      a2 = fmaf(u_s[hh * ND + d], w_v[(size_t)(hh * ND + d) * NE + tid], a2);
    uv[hh * NE + tid] = a2;
  }
  if (tid == 0) {
    float cc = 0.f;
    for (int j = 0; j < NE; ++j) cc = fmaf(wbd_s[j], b_o[j], cc);
    consts[0] = cc + b_bd[0];
  }
  if (tid >= 4 && tid < 8) {
    const int hh = tid - 4;
    float cv = 0.f;
    for (int d = 0; d < ND; ++d) cv = fmaf(u_s[hh * ND + d], b_v[hh * ND + d], cv);
    consts[1 + hh] = cv;
  }
  for (int i = tid; i < NB * NP * NE; i += 256) psum[i] = 0.f;
}

// ---------------- generic f32 GEMM: C = A[M,256] @ W[N,256]^T + bias ----------------
// BM=128 BN=64 BK=32, 256 threads, 8x4 per-thread tile.
// mode 0: Cf[row*256+n] (f32); mode 1: bf16 hi/lo split, head layout
__global__ __launch_bounds__(256) void gemm_kernel(
    const float* __restrict__ A, const float* __restrict__ W,
    const float* __restrict__ bias, float* __restrict__ Cf,
    unsigned short* __restrict__ Chi, unsigned short* __restrict__ Clo, int mode)
{
  __shared__ float a_s[32][132];
  __shared__ float b_s[32][68];
  const int tid = threadIdx.x;
  const int m0 = blockIdx.x * 128;
  const int n0 = blockIdx.y * 64;
  const int tm = tid >> 4, tn = tid & 15;
  const int r0 = tm * 8, c0 = tn * 4;
  float acc[8][4] = {};
  for (int k0 = 0; k0 < NE; k0 += 32) {
    #pragma unroll
    for (int i = 0; i < 4; ++i) {
      const int idx = i * 256 + tid;
      const int row = idx >> 3, kq = idx & 7;
      const float4 v = *(const float4*)(A + (size_t)(m0 + row) * NE + k0 + kq * 4);
      a_s[kq * 4 + 0][row] = v.x; a_s[kq * 4 + 1][row] = v.y;
      a_s[kq * 4 + 2][row] = v.z; a_s[kq * 4 + 3][row] = v.w;
    }
    #pragma unroll
    for (int i = 0; i < 2; ++i) {
      const int idx = i * 256 + tid;
      const int row = idx >> 3, kq = idx & 7;
      const float4 v = *(const float4*)(W + (size_t)(n0 + row) * NE + k0 + kq * 4);
      b_s[kq * 4 + 0][row] = v.x; b_s[kq * 4 + 1][row] = v.y;
      b_s[kq * 4 + 2][row] = v.z; b_s[kq * 4 + 3][row] = v.w;
    }
    __syncthreads();
    #pragma unroll 8
    for (int kk = 0; kk < 32; ++kk) {
      const float4 a0 = *(const float4*)&a_s[kk][r0];
      const float4 a1 = *(const float4*)&a_s[kk][r0 + 4];
      const float4 bv = *(const float4*)&b_s[kk][c0];
      const float av[8] = {a0.x, a0.y, a0.z, a0.w, a1.x, a1.y, a1.z, a1.w};
      const float bb[4] = {bv.x, bv.y, bv.z, bv.w};
      #pragma unroll
      for (int i = 0; i < 8; ++i)
        #pragma unroll
        for (int j = 0; j < 4; ++j)
          acc[i][j] = fmaf(av[i], bb[j], acc[i][j]);
    }
    __syncthreads();
  }
  #pragma unroll
  for (int i = 0; i < 8; ++i) {
    const int row = m0 + r0 + i;
    #pragma unroll
    for (int j = 0; j < 4; ++j) {
      const int n = n0 + c0 + j;
      const float v = acc[i][j] + bias[n];
      if (mode == 0) {
        Cf[(size_t)row * NE + n] = v;
      } else {
        const int head = n >> 6, d = n & 63;
        const int b = row >> 11, t = row & 2047;
        const size_t idx = (((size_t)(b * NH + head)) * NT + t) * ND + d;
        const unsigned short hb = f2bf(v);
        Chi[idx] = hb;
        Clo[idx] = f2bf(v - bf2f(hb));
      }
    }
  }
}

// ---------------- vu[b,h,t] = h_row . uv_h + cv_h (one wave per token) ----------------
__global__ __launch_bounds__(256) void vu_kernel(
    const float* __restrict__ h, const float* __restrict__ uv,
    const float* __restrict__ consts, float* __restrict__ vuout)
{
  __shared__ float uv_s[NH][NE];
  const int tid = threadIdx.x;
  #pragma unroll
  for (int i = 0; i < 4; ++i) { const int idx = i * 256 + tid; uv_s[idx >> 8][idx & 255] = uv[idx]; }
  __syncthreads();
  const int wave = tid >> 6, lane = tid & 63;
  const int token = blockIdx.x * 4 + wave;            // = b*NT + t
  const float4 hv = *(const float4*)(h + (size_t)token * NE + lane * 4);
  const int b = token >> 11, t = token & 2047;
  #pragma unroll
  for (int hh = 0; hh < NH; ++hh) {
    float p = hv.x * uv_s[hh][lane * 4 + 0] + hv.y * uv_s[hh][lane * 4 + 1]
            + hv.z * uv_s[hh][lane * 4 + 2] + hv.w * uv_s[hh][lane * 4 + 3];
    #pragma unroll
    for (int off = 32; off > 0; off >>= 1) p += __shfl_down(p, off);
    if (lane == 0) vuout[((size_t)(b * NH + hh)) * NT + t] = p + consts[1 + hh];
  }
}

// ---------------- attention via bf16 MFMA with hi/lo compensation --------------------
// sp[b,t,h] = softmax(q.k/8) . vu   using mfma_f32_16x16x32_bf16, no LDS.
// Block = 4 waves; wave owns 32 q-rows; k-tile = 64 cols/iter.
// A-frag = q[row][k] with row=lane&15, k=8*(lane>>4)+i  (direct 16B load from [t][d])
// B-frag = k[col][k] same pattern; D: col=lane&15, row=4*(lane>>4)+reg.
__global__ __launch_bounds__(256) void attn_mfma_kernel(
    const unsigned short* __restrict__ qhi, const unsigned short* __restrict__ qlo,
    const unsigned short* __restrict__ khi, const unsigned short* __restrict__ klo,
    const float* __restrict__ vu, float* __restrict__ sp)
{
  const int tid = threadIdx.x;
  const int wave = tid >> 6, lane = tid & 63;
  const int lr = lane & 15;          // A-row / B-col / D-col
  const int lg = lane >> 4;          // k-group; D-row-group
  // XCD-aware decode: blocks with bid%8==c handle bh in [4c,4c+4) -> K fits 4MiB L2
  const int bid = blockIdx.x;        // 0..511
  const int xcd = bid & 7;
  const int inx = bid >> 3;          // 0..63
  const int bh  = xcd * 4 + (inx >> 4);
  const int qt  = inx & 15;
  const int b = bh >> 2, hh = bh & 3;
  const size_t base = (size_t)bh * NT * ND;
  const int qrow0 = qt * 128 + wave * 32;
  const float* vub = vu + (size_t)bh * NT;

  // Q fragments, hoisted (read once): [m-subtile][d-slice][hi/lo]
  bf16x8 qf[2][2][2];
  #pragma unroll
  for (int s = 0; s < 2; ++s)
    #pragma unroll
    for (int ds = 0; ds < 2; ++ds) {
      const size_t off = base + (size_t)(qrow0 + s * 16 + lr) * ND + ds * 32 + lg * 8;
      qf[s][ds][0] = *(const bf16x8*)(qhi + off);
      qf[s][ds][1] = *(const bf16x8*)(qlo + off);
    }

  float m[8], l[8], sv[8];
  #pragma unroll
  for (int i = 0; i < 8; ++i) { m[i] = -1e30f; l[i] = 0.f; sv[i] = 0.f; }

  for (int kt = 0; kt < 32; ++kt) {
    f32x4 acc[2][4];
    #pragma unroll
    for (int s = 0; s < 2; ++s)
      #pragma unroll
      for (int ns = 0; ns < 4; ++ns)
        acc[s][ns] = (f32x4){0.f, 0.f, 0.f, 0.f};
    float vuv[4];
    #pragma unroll
    for (int ns = 0; ns < 4; ++ns) {
      // B-frags for this n-subtile
      bf16x8 kh0, kh1, kl0, kl1;
      {
        const size_t off = base + (size_t)(kt * 64 + ns * 16 + lr) * ND + lg * 8;
        kh0 = *(const bf16x8*)(khi + off);
        kl0 = *(const bf16x8*)(klo + off);
        kh1 = *(const bf16x8*)(khi + off + 32);
        kl1 = *(const bf16x8*)(klo + off + 32);
      }
      vuv[ns] = vub[kt * 64 + ns * 16 + lr];
      #pragma unroll
      for (int s = 0; s < 2; ++s) {
        acc[s][ns] = __builtin_amdgcn_mfma_f32_16x16x32_bf16(qf[s][0][0], kh0, acc[s][ns], 0, 0, 0);
        acc[s][ns] = __builtin_amdgcn_mfma_f32_16x16x32_bf16(qf[s][0][0], kl0, acc[s][ns], 0, 0, 0);
        acc[s][ns] = __builtin_amdgcn_mfma_f32_16x16x32_bf16(qf[s][0][1], kh0, acc[s][ns], 0, 0, 0);
        acc[s][ns] = __builtin_amdgcn_mfma_f32_16x16x32_bf16(qf[s][1][0], kh1, acc[s][ns], 0, 0, 0);
        acc[s][ns] = __builtin_amdgcn_mfma_f32_16x16x32_bf16(qf[s][1][0], kl1, acc[s][ns], 0, 0, 0);
        acc[s][ns] = __builtin_amdgcn_mfma_f32_16x16x32_bf16(qf[s][1][1], kh1, acc[s][ns], 0, 0, 0);
      }
    }
    // online softmax + vu-weighted accumulation, fully in registers
    #pragma unroll
    for (int s = 0; s < 2; ++s)
      #pragma unroll
      for (int reg = 0; reg < 4; ++reg) {
        const int ri = s * 4 + reg;
        float mx = fmaxf(fmaxf(acc[s][0][reg], acc[s][1][reg]),
                         fmaxf(acc[s][2][reg], acc[s][3][reg]));
        mx = fmaxf(mx, __shfl_xor(mx, 1, 16));
        mx = fmaxf(mx, __shfl_xor(mx, 2, 16));
        mx = fmaxf(mx, __shfl_xor(mx, 4, 16));
        mx = fmaxf(mx, __shfl_xor(mx, 8, 16));
        mx *= 0.125f;                       // exact (pow2)
        const float mn = fmaxf(m[ri], mx);
        const float al = __expf(m[ri] - mn);
        float es = 0.f, ev = 0.f;
        #pragma unroll
        for (int ns = 0; ns < 4; ++ns) {
          const float e = __expf(fmaf(acc[s][ns][reg], 0.125f, -mn));
          es += e;
          ev = fmaf(e, vuv[ns], ev);
        }
        l[ri]  = fmaf(l[ri], al, es);
        sv[ri] = fmaf(sv[ri], al, ev);
        m[ri] = mn;
      }
  }
  // reduce partial l/sv across the 16-lane column group
  #pragma unroll
  for (int ri = 0; ri < 8; ++ri) {
    #pragma unroll
    for (int off = 1; off < 16; off <<= 1) {
      l[ri]  += __shfl_xor(l[ri],  off, 16);
      sv[ri] += __shfl_xor(sv[ri], off, 16);
    }
  }
  if (lr == 0) {
    #pragma unroll
    for (int s = 0; s < 2; ++s)
      #pragma unroll
      for (int reg = 0; reg < 4; ++reg) {
        const int row = qrow0 + s * 16 + lg * 4 + reg;
        sp[((size_t)b * NT + row) * NH + hh] = sv[s * 4 + reg] / l[s * 4 + reg];
      }
  }
}

// ---------------- boundary: sigmoid, cumsum, pid, counts (one block per batch) --------
__global__ __launch_bounds__(256) void boundary_kernel(
    const float* __restrict__ sp, const float* __restrict__ consts,
    int* __restrict__ pid, int* __restrict__ counts)
{
  const int b = blockIdx.x, tid = threadIdx.x;
  __shared__ float partial[256];
  __shared__ int cnt_s[8];
  const float c = consts[0];
  float v[8];
  float run = 0.f;
  #pragma unroll
  for (int i = 0; i < 8; ++i) {
    const int t = tid * 8 + i;
    const float* p = sp + ((size_t)b * NT + t) * NH;
    const float logit = p[0] + p[1] + p[2] + p[3] + c;
    const float bs = 1.f / (1.f + expf(-logit));
    run += bs;
    v[i] = run;
  }
  float x = run;
  partial[tid] = x;
  __syncthreads();
  for (int off = 1; off < 256; off <<= 1) {
    const float y = (tid >= off) ? partial[tid - off] : 0.f;
    __syncthreads();
    x += y;
    partial[tid] = x;
    __syncthreads();
  }
  const float total = partial[255];
  if (tid < 8) cnt_s[tid] = 0;
  __syncthreads();
  const float denom = fmaxf(total, 1e-6f);
  const float excl = x - run;
  #pragma unroll
  for (int i = 0; i < 8; ++i) {
    const float norm = (excl + v[i]) / denom;
    int pp = (int)(norm * 8.f);
    pp = pp > 7 ? 7 : pp;
    pid[b * NT + tid * 8 + i] = pp;
    atomicAdd(&cnt_s[pp], 1);
  }
  __syncthreads();
  if (tid < 8) counts[b * 8 + tid] = cnt_s[tid];
}

// ---------------- pool h into patch sums (branchless 8-way select) --------------------
__global__ __launch_bounds__(256) void pool_kernel(
    const float* __restrict__ h, const int* __restrict__ pid, float* __restrict__ psum)
{
  const int b = blockIdx.x >> 3, chunk = blockIdx.x & 7;
  const int tid = threadIdx.x;
  __shared__ int pid_s[256];
  const int t0 = chunk * 256;
  pid_s[tid] = pid[b * NT + t0 + tid];
  __syncthreads();
  float acc[8] = {};
  for (int tok = 0; tok < 256; ++tok) {
    const float val = h[((size_t)b * NT + t0 + tok) * NE + tid];
    const int p = pid_s[tok];
    #pragma unroll
    for (int pp = 0; pp < 8; ++pp) acc[pp] += (p == pp) ? val : 0.f;
  }
  #pragma unroll
  for (int pp = 0; pp < 8; ++pp)
    atomicAdd(&psum[((size_t)b * NP + pp) * NE + tid], acc[pp]);
}

// ---------------- final: out = (psum/count) @ w_pr^T + b_pr --------------------------
__global__ __launch_bounds__(256) void final_kernel(
    const float* __restrict__ psum, const int* __restrict__ counts,
    const float* __restrict__ w_pr, const float* __restrict__ b_pr, float* __restrict__ out)
{
  const int bp = blockIdx.x;
  const int tid = threadIdx.x;
  __shared__ float pe[NE];
  const float cnt = fmaxf((float)counts[bp], 1.f);
  pe[tid] = psum[(size_t)bp * NE + tid] / cnt;
  __syncthreads();
  float acc = 0.f;
  for (int e = 0; e < NE; ++e) acc = fmaf(pe[e], w_pr[(size_t)tid * NE + e], acc);
  out[(size_t)bp * NE + tid] = acc + b_pr[tid];
}

extern "C" void kernel_launch(void* const* d_in, const int* in_sizes, int n_in,
                              void* d_out, int out_size, void* d_ws, size_t ws_size,
                              hipStream_t stream) {
  (void)in_sizes; (void)n_in; (void)out_size; (void)ws_size;
  const float* x    = (const float*)d_in[0];
  const float* w_in = (const float*)d_in[1];
  const float* b_in = (const float*)d_in[2];
  const float* w_q  = (const float*)d_in[3];
  const float* b_q  = (const float*)d_in[4];
  const float* w_k  = (const float*)d_in[5];
  const float* b_k  = (const float*)d_in[6];
  const float* w_v  = (const float*)d_in[7];
  const float* b_v  = (const float*)d_in[8];
  const float* w_o  = (const float*)d_in[9];
  const float* b_o  = (const float*)d_in[10];
  const float* w_bd = (const float*)d_in[11];
  const float* b_bd = (const float*)d_in[12];
  const float* w_pr = (const float*)d_in[13];
  const float* b_pr = (const float*)d_in[14];
  float* out = (float*)d_out;
  float* ws = (float*)d_ws;

  float* hbuf = ws;                                       // 4194304 f32
  unsigned short* qhi = (unsigned short*)(hbuf + 4194304);// 4194304 u16 each
  unsigned short* qlo = qhi + 4194304;
  unsigned short* khi = qlo + 4194304;
  unsigned short* klo = khi + 4194304;
  float* vubuf  = (float*)(klo + 4194304);                // 65536 [B,H,T]
  float* spbuf  = vubuf + 65536;                          // 65536 [B,T,H]
  float* uvbuf  = spbuf + 65536;                          // 1024
  float* consts = uvbuf + 1024;                           // 8
  float* psum   = consts + 8;                             // 16384
  int*   pid    = (int*)(psum + 16384);                   // 16384
  int*   counts = pid + 16384;                            // 64

  prep_kernel<<<1, 256, 0, stream>>>(w_o, b_o, w_bd, b_bd, w_v, b_v, uvbuf, consts, psum);
  gemm_kernel<<<dim3(128, 4), 256, 0, stream>>>(x, w_in, b_in, hbuf, nullptr, nullptr, 0);
  gemm_kernel<<<dim3(128, 4), 256, 0, stream>>>(hbuf, w_q, b_q, nullptr, qhi, qlo, 1);
  gemm_kernel<<<dim3(128, 4), 256, 0, stream>>>(hbuf, w_k, b_k, nullptr, khi, klo, 1);
  vu_kernel<<<4096, 256, 0, stream>>>(hbuf, uvbuf, consts, vubuf);
  attn_mfma_kernel<<<512, 256, 0, stream>>>(qhi, qlo, khi, klo, vubuf, spbuf);
  boundary_kernel<<<8, 256, 0, stream>>>(spbuf, consts, pid, counts);
  pool_kernel<<<64, 256, 0, stream>>>(hbuf, pid, psum);
  final_kernel<<<64, 256, 0, stream>>>(psum, counts, w_pr, b_pr, out);
}

// Round 3
// 220.904 us; speedup vs baseline: 2.1248x; 1.4228x over previous
//
#include <hip/hip_runtime.h>
#include <cstddef>

#define NB 8
#define NT 2048
#define NE 256
#define NH 4
#define ND 64
#define NP 8

typedef short bf16x8 __attribute__((ext_vector_type(8)));
typedef float f32x4 __attribute__((ext_vector_type(4)));

__device__ __forceinline__ unsigned short f2bf(float f) {
  unsigned u = __builtin_bit_cast(unsigned, f);
  u += 0x7fffu + ((u >> 16) & 1u);          // RNE
  return (unsigned short)(u >> 16);
}
__device__ __forceinline__ float bf2f(unsigned short h) {
  unsigned u = ((unsigned)h) << 16;
  return __builtin_bit_cast(float, u);
}

// ---------------- prep: u = w_bd @ w_o ; uv_h = u_h @ w_v slice ; consts ; zero psum ----
__global__ __launch_bounds__(256) void prep_kernel(
    const float* __restrict__ w_o, const float* __restrict__ b_o,
    const float* __restrict__ w_bd, const float* __restrict__ b_bd,
    const float* __restrict__ w_v, const float* __restrict__ b_v,
    float* __restrict__ uv, float* __restrict__ consts, float* __restrict__ psum)
{
  __shared__ float wbd_s[NE];
  __shared__ float u_s[NE];
  const int tid = threadIdx.x;
  wbd_s[tid] = w_bd[tid];
  __syncthreads();
  float a = 0.f;
  for (int j = 0; j < NE; ++j) a = fmaf(wbd_s[j], w_o[j * NE + tid], a);
  u_s[tid] = a;
  __syncthreads();
  #pragma unroll
  for (int hh = 0; hh < NH; ++hh) {
    float a2 = 0.f;
    for (int d = 0; d < ND; ++d)
      a2 = fmaf(u_s[hh * ND + d], w_v[(size_t)(hh * ND + d) * NE + tid], a2);
    uv[hh * NE + tid] = a2;
  }
  if (tid == 0) {
    float cc = 0.f;
    for (int j = 0; j < NE; ++j) cc = fmaf(wbd_s[j], b_o[j], cc);
    consts[0] = cc + b_bd[0];
  }
  if (tid >= 4 && tid < 8) {
    const int hh = tid - 4;
    float cv = 0.f;
    for (int d = 0; d < ND; ++d) cv = fmaf(u_s[hh * ND + d], b_v[hh * ND + d], cv);
    consts[1 + hh] = cv;
  }
  for (int i = tid; i < NB * NP * NE; i += 256) psum[i] = 0.f;
}

// ---------------- generic f32 -> bf16 hi/lo split --------------------------------------
__global__ __launch_bounds__(256) void split_kernel(
    const float* __restrict__ in, unsigned short* __restrict__ hi,
    unsigned short* __restrict__ lo, int n4)
{
  const int stride = gridDim.x * 256;
  for (int i = blockIdx.x * 256 + threadIdx.x; i < n4; i += stride) {
    const float4 v = *(const float4*)(in + (size_t)i * 4);
    const float vv[4] = {v.x, v.y, v.z, v.w};
    unsigned short h4[4], l4[4];
    #pragma unroll
    for (int j = 0; j < 4; ++j) {
      h4[j] = f2bf(vv[j]);
      l4[j] = f2bf(vv[j] - bf2f(h4[j]));
    }
    *(ushort2*)(hi + (size_t)i * 4)     = make_ushort2(h4[0], h4[1]);
    *(ushort2*)(hi + (size_t)i * 4 + 2) = make_ushort2(h4[2], h4[3]);
    *(ushort2*)(lo + (size_t)i * 4)     = make_ushort2(l4[0], l4[1]);
    *(ushort2*)(lo + (size_t)i * 4 + 2) = make_ushort2(l4[2], l4[3]);
  }
}

// ---------------- w_q & w_k concat split [512][256] + combined bias --------------------
__global__ __launch_bounds__(256) void wqk_kernel(
    const float* __restrict__ w_q, const float* __restrict__ w_k,
    const float* __restrict__ b_q, const float* __restrict__ b_k,
    unsigned short* __restrict__ hi, unsigned short* __restrict__ lo,
    float* __restrict__ bias)
{
  const int i = blockIdx.x * 256 + threadIdx.x;   // grid 512 -> 131072 elems
  const float v = (i < 65536) ? w_q[i] : w_k[i - 65536];
  const unsigned short h = f2bf(v);
  hi[i] = h;
  lo[i] = f2bf(v - bf2f(h));
  if (i < 512) bias[i] = (i < 256) ? b_q[i] : b_k[i - 256];
}

// ---------------- compensated bf16 MFMA GEMM: C = (Ahi+Alo)(Whi+Wlo)^T + bias ----------
// K=256. Block 256 thr = 4 waves; tile 128 rows x 64 cols; wave = 32 rows.
// MODE 0: Cf f32 [M][256] + Chi/Clo bf16 [M][256].  MODE 1: q/k head-split hi/lo.
template <int MODE>
__global__ __launch_bounds__(256) void mgemm_kernel(
    const unsigned short* __restrict__ Ahi, const unsigned short* __restrict__ Alo,
    const unsigned short* __restrict__ Whi, const unsigned short* __restrict__ Wlo,
    const float* __restrict__ bias,
    float* __restrict__ Cf, unsigned short* __restrict__ Chi, unsigned short* __restrict__ Clo,
    unsigned short* __restrict__ Qhi, unsigned short* __restrict__ Qlo,
    unsigned short* __restrict__ Khi, unsigned short* __restrict__ Klo)
{
  const int tid = threadIdx.x;
  const int wave = tid >> 6, lane = tid & 63;
  const int lr = lane & 15, lg = lane >> 4;
  const int m0 = blockIdx.x * 128, n0 = blockIdx.y * 64;
  const int wrow0 = m0 + wave * 32;
  f32x4 acc[2][4];
  #pragma unroll
  for (int s = 0; s < 2; ++s)
    #pragma unroll
    for (int ns = 0; ns < 4; ++ns) acc[s][ns] = (f32x4){0.f, 0.f, 0.f, 0.f};

  #pragma unroll 2
  for (int k0 = 0; k0 < 256; k0 += 32) {
    bf16x8 a[2][2], bf[4][2];
    #pragma unroll
    for (int s = 0; s < 2; ++s) {
      const size_t off = (size_t)(wrow0 + s * 16 + lr) * 256 + k0 + lg * 8;
      a[s][0] = *(const bf16x8*)(Ahi + off);
      a[s][1] = *(const bf16x8*)(Alo + off);
    }
    #pragma unroll
    for (int ns = 0; ns < 4; ++ns) {
      const size_t off = (size_t)(n0 + ns * 16 + lr) * 256 + k0 + lg * 8;
      bf[ns][0] = *(const bf16x8*)(Whi + off);
      bf[ns][1] = *(const bf16x8*)(Wlo + off);
    }
    #pragma unroll
    for (int s = 0; s < 2; ++s)
      #pragma unroll
      for (int ns = 0; ns < 4; ++ns) {
        acc[s][ns] = __builtin_amdgcn_mfma_f32_16x16x32_bf16(a[s][0], bf[ns][0], acc[s][ns], 0, 0, 0);
        acc[s][ns] = __builtin_amdgcn_mfma_f32_16x16x32_bf16(a[s][0], bf[ns][1], acc[s][ns], 0, 0, 0);
        acc[s][ns] = __builtin_amdgcn_mfma_f32_16x16x32_bf16(a[s][1], bf[ns][0], acc[s][ns], 0, 0, 0);
      }
  }
  // epilogue: D layout col=lane&15, row=4*(lane>>4)+reg
  #pragma unroll
  for (int s = 0; s < 2; ++s)
    #pragma unroll
    for (int ns = 0; ns < 4; ++ns)
      #pragma unroll
      for (int reg = 0; reg < 4; ++reg) {
        const int row = wrow0 + s * 16 + lg * 4 + reg;
        const int col = n0 + ns * 16 + lr;
        const float v = acc[s][ns][reg] + bias[col];
        if (MODE == 0) {
          const size_t idx = (size_t)row * 256 + col;
          Cf[idx] = v;
          const unsigned short hb = f2bf(v);
          Chi[idx] = hb;
          Clo[idx] = f2bf(v - bf2f(hb));
        } else {
          const int c = col & 255;
          const int head = c >> 6, d = c & 63;
          const int b = row >> 11, t = row & 2047;
          const size_t idx = (((size_t)(b * NH + head)) * NT + t) * ND + d;
          const unsigned short hb = f2bf(v);
          if (col < 256) { Qhi[idx] = hb; Qlo[idx] = f2bf(v - bf2f(hb)); }
          else           { Khi[idx] = hb; Klo[idx] = f2bf(v - bf2f(hb)); }
        }
      }
}

// ---------------- vu[b,h,t] = h_row . uv_h + cv_h (one wave per token) ----------------
__global__ __launch_bounds__(256) void vu_kernel(
    const float* __restrict__ h, const float* __restrict__ uv,
    const float* __restrict__ consts, float* __restrict__ vuout)
{
  __shared__ float uv_s[NH][NE];
  const int tid = threadIdx.x;
  #pragma unroll
  for (int i = 0; i < 4; ++i) { const int idx = i * 256 + tid; uv_s[idx >> 8][idx & 255] = uv[idx]; }
  __syncthreads();
  const int wave = tid >> 6, lane = tid & 63;
  const int token = blockIdx.x * 4 + wave;            // = b*NT + t
  const float4 hv = *(const float4*)(h + (size_t)token * NE + lane * 4);
  const int b = token >> 11, t = token & 2047;
  #pragma unroll
  for (int hh = 0; hh < NH; ++hh) {
    float p = hv.x * uv_s[hh][lane * 4 + 0] + hv.y * uv_s[hh][lane * 4 + 1]
            + hv.z * uv_s[hh][lane * 4 + 2] + hv.w * uv_s[hh][lane * 4 + 3];
    #pragma unroll
    for (int off = 32; off > 0; off >>= 1) p += __shfl_down(p, off);
    if (lane == 0) vuout[((size_t)(b * NH + hh)) * NT + t] = p + consts[1 + hh];
  }
}

// ---------------- attention v3: LDS-shared K tiles, 8 waves, swizzled ------------------
// sp[b,t,h] = softmax(q.k/8) . vu ; block = 512 thr, 128 q-rows (16/wave); k-tile 64.
__global__ __launch_bounds__(512) void attn_kernel3(
    const unsigned short* __restrict__ qhi, const unsigned short* __restrict__ qlo,
    const unsigned short* __restrict__ khi, const unsigned short* __restrict__ klo,
    const float* __restrict__ vu, float* __restrict__ sp)
{
  __shared__ __align__(16) char kbuf[2][16384];   // [buf][hi 8KB | lo 8KB], XOR-swizzled
  __shared__ float vu_s[NT];
  const int tid = threadIdx.x;
  const int wave = tid >> 6, lane = tid & 63;
  const int lr = lane & 15, lg = lane >> 4;
  // XCD-aware decode: 512 blocks; bh grouped per XCD for K L2 locality
  const int bid = blockIdx.x;
  const int bh = (bid & 7) * 4 + ((bid >> 3) >> 4);
  const int qt = (bid >> 3) & 15;
  const int b = bh >> 2, hh = bh & 3;
  const size_t base = (size_t)bh * NT * ND;
  const int qrow0 = qt * 128 + wave * 16;

  // stage vu (whole bh row, 8KB)
  {
    const float4 v = *(const float4*)(vu + base / ND + tid * 4);
    *(float4*)&vu_s[tid * 4] = v;
  }
  // Q fragments (held in regs): [d-slice][hi/lo]
  bf16x8 qf[2][2];
  #pragma unroll
  for (int ds = 0; ds < 2; ++ds) {
    const size_t off = base + (size_t)(qrow0 + lr) * ND + ds * 32 + lg * 8;
    qf[ds][0] = *(const bf16x8*)(qhi + off);
    qf[ds][1] = *(const bf16x8*)(qlo + off);
  }
  // staging addresses: thread covers 16B of hi and 16B of lo per 64x64 tile
  const int o = tid * 16;                               // linear byte in 8KB tile
  const int so = o ^ (((o >> 7) & 7) << 4);             // swizzled LDS offset
  // read offsets (per ns, per d-slice), same swizzle
  int ro0[4], ro1[4];
  #pragma unroll
  for (int ns = 0; ns < 4; ++ns) {
    const int r = ns * 16 + lr;
    const int sw = (r & 7) << 4;
    const int ob = r * 128 + lg * 16;
    ro0[ns] = ob ^ sw;
    ro1[ns] = (ob + 64) ^ sw;
  }
  // prologue: stage tile 0
  {
    const bf16x8 sh = *(const bf16x8*)(khi + base + tid * 8);
    const bf16x8 sl = *(const bf16x8*)(klo + base + tid * 8);
    *(bf16x8*)&kbuf[0][so] = sh;
    *(bf16x8*)&kbuf[0][8192 + so] = sl;
  }
  __syncthreads();

  float m[4], l[4], sv[4];
  #pragma unroll
  for (int i = 0; i < 4; ++i) { m[i] = -1e30f; l[i] = 0.f; sv[i] = 0.f; }

  for (int kt = 0; kt < 32; ++kt) {
    bf16x8 nh, nl;
    if (kt < 31) {                                      // issue next-tile loads early
      nh = *(const bf16x8*)(khi + base + (size_t)(kt + 1) * 4096 + tid * 8);
      nl = *(const bf16x8*)(klo + base + (size_t)(kt + 1) * 4096 + tid * 8);
    }
    const char* kb = (const char*)kbuf[kt & 1];
    f32x4 acc[4];
    float vuv[4];
    #pragma unroll
    for (int ns = 0; ns < 4; ++ns) {
      acc[ns] = (f32x4){0.f, 0.f, 0.f, 0.f};
      const bf16x8 kh0 = *(const bf16x8*)(kb + ro0[ns]);
      const bf16x8 kh1 = *(const bf16x8*)(kb + ro1[ns]);
      const bf16x8 kl0 = *(const bf16x8*)(kb + 8192 + ro0[ns]);
      const bf16x8 kl1 = *(const bf16x8*)(kb + 8192 + ro1[ns]);
      vuv[ns] = vu_s[kt * 64 + ns * 16 + lr];
      acc[ns] = __builtin_amdgcn_mfma_f32_16x16x32_bf16(qf[0][0], kh0, acc[ns], 0, 0, 0);
      acc[ns] = __builtin_amdgcn_mfma_f32_16x16x32_bf16(qf[0][0], kl0, acc[ns], 0, 0, 0);
      acc[ns] = __builtin_amdgcn_mfma_f32_16x16x32_bf16(qf[0][1], kh0, acc[ns], 0, 0, 0);
      acc[ns] = __builtin_amdgcn_mfma_f32_16x16x32_bf16(qf[1][0], kh1, acc[ns], 0, 0, 0);
      acc[ns] = __builtin_amdgcn_mfma_f32_16x16x32_bf16(qf[1][0], kl1, acc[ns], 0, 0, 0);
      acc[ns] = __builtin_amdgcn_mfma_f32_16x16x32_bf16(qf[1][1], kh1, acc[ns], 0, 0, 0);
    }
    // online softmax + vu accumulation (rows = 4*lg+reg of this wave's 16)
    #pragma unroll
    for (int reg = 0; reg < 4; ++reg) {
      float mx = fmaxf(fmaxf(acc[0][reg], acc[1][reg]), fmaxf(acc[2][reg], acc[3][reg]));
      mx = fmaxf(mx, __shfl_xor(mx, 1, 16));
      mx = fmaxf(mx, __shfl_xor(mx, 2, 16));
      mx = fmaxf(mx, __shfl_xor(mx, 4, 16));
      mx = fmaxf(mx, __shfl_xor(mx, 8, 16));
      mx *= 0.125f;                                     // exact (pow2)
      const float mn = fmaxf(m[reg], mx);
      const float al = __expf(m[reg] - mn);
      float es = 0.f, ev = 0.f;
      #pragma unroll
      for (int ns = 0; ns < 4; ++ns) {
        const float e = __expf(fmaf(acc[ns][reg], 0.125f, -mn));
        es += e;
        ev = fmaf(e, vuv[ns], ev);
      }
      l[reg]  = fmaf(l[reg], al, es);
      sv[reg] = fmaf(sv[reg], al, ev);
      m[reg] = mn;
    }
    __syncthreads();                                    // (A) everyone done reading other buf
    if (kt < 31) {
      *(bf16x8*)&kbuf[(kt + 1) & 1][so] = nh;
      *(bf16x8*)&kbuf[(kt + 1) & 1][8192 + so] = nl;
    }
    __syncthreads();                                    // (B) writes visible
  }
  // reduce partial l/sv across the 16-lane column group
  #pragma unroll
  for (int reg = 0; reg < 4; ++reg) {
    #pragma unroll
    for (int off = 1; off < 16; off <<= 1) {
      l[reg]  += __shfl_xor(l[reg],  off, 16);
      sv[reg] += __shfl_xor(sv[reg], off, 16);
    }
  }
  if (lr == 0) {
    #pragma unroll
    for (int reg = 0; reg < 4; ++reg) {
      const int row = qrow0 + lg * 4 + reg;
      sp[((size_t)b * NT + row) * NH + hh] = sv[reg] / l[reg];
    }
  }
}

// ---------------- boundary: sigmoid, cumsum, pid, counts (one block per batch) --------
__global__ __launch_bounds__(256) void boundary_kernel(
    const float* __restrict__ sp, const float* __restrict__ consts,
    int* __restrict__ pid, int* __restrict__ counts)
{
  const int b = blockIdx.x, tid = threadIdx.x;
  __shared__ float partial[256];
  __shared__ int cnt_s[8];
  const float c = consts[0];
  float v[8];
  float run = 0.f;
  #pragma unroll
  for (int i = 0; i < 8; ++i) {
    const int t = tid * 8 + i;
    const float* p = sp + ((size_t)b * NT + t) * NH;
    const float logit = p[0] + p[1] + p[2] + p[3] + c;
    const float bs = 1.f / (1.f + expf(-logit));
    run += bs;
    v[i] = run;
  }
  float x = run;
  partial[tid] = x;
  __syncthreads();
  for (int off = 1; off < 256; off <<= 1) {
    const float y = (tid >= off) ? partial[tid - off] : 0.f;
    __syncthreads();
    x += y;
    partial[tid] = x;
    __syncthreads();
  }
  const float total = partial[255];
  if (tid < 8) cnt_s[tid] = 0;
  __syncthreads();
  const float denom = fmaxf(total, 1e-6f);
  const float excl = x - run;
  #pragma unroll
  for (int i = 0; i < 8; ++i) {
    const float norm = (excl + v[i]) / denom;
    int pp = (int)(norm * 8.f);
    pp = pp > 7 ? 7 : pp;
    pid[b * NT + tid * 8 + i] = pp;
    atomicAdd(&cnt_s[pp], 1);
  }
  __syncthreads();
  if (tid < 8) counts[b * 8 + tid] = cnt_s[tid];
}

// ---------------- pool h into patch sums (branchless 8-way select) --------------------
__global__ __launch_bounds__(256) void pool_kernel(
    const float* __restrict__ h, const int* __restrict__ pid, float* __restrict__ psum)
{
  const int b = blockIdx.x >> 4, chunk = blockIdx.x & 15;
  const int tid = threadIdx.x;
  __shared__ int pid_s[128];
  const int t0 = chunk * 128;
  if (tid < 128) pid_s[tid] = pid[b * NT + t0 + tid];
  __syncthreads();
  float acc[8] = {};
  for (int tok = 0; tok < 128; ++tok) {
    const float val = h[((size_t)b * NT + t0 + tok) * NE + tid];
    const int p = pid_s[tok];
    #pragma unroll
    for (int pp = 0; pp < 8; ++pp) acc[pp] += (p == pp) ? val : 0.f;
  }
  #pragma unroll
  for (int pp = 0; pp < 8; ++pp)
    atomicAdd(&psum[((size_t)b * NP + pp) * NE + tid], acc[pp]);
}

// ---------------- final: out = (psum/count) @ w_pr^T + b_pr --------------------------
__global__ __launch_bounds__(256) void final_kernel(
    const float* __restrict__ psum, const int* __restrict__ counts,
    const float* __restrict__ w_pr, const float* __restrict__ b_pr, float* __restrict__ out)
{
  const int bp = blockIdx.x;
  const int tid = threadIdx.x;
  __shared__ float pe[NE];
  const float cnt = fmaxf((float)counts[bp], 1.f);
  pe[tid] = psum[(size_t)bp * NE + tid] / cnt;
  __syncthreads();
  float acc = 0.f;
  for (int e = 0; e < NE; ++e) acc = fmaf(pe[e], w_pr[(size_t)tid * NE + e], acc);
  out[(size_t)bp * NE + tid] = acc + b_pr[tid];
}

extern "C" void kernel_launch(void* const* d_in, const int* in_sizes, int n_in,
                              void* d_out, int out_size, void* d_ws, size_t ws_size,
                              hipStream_t stream) {
  (void)in_sizes; (void)n_in; (void)out_size; (void)ws_size;
  const float* x    = (const float*)d_in[0];
  const float* w_in = (const float*)d_in[1];
  const float* b_in = (const float*)d_in[2];
  const float* w_q  = (const float*)d_in[3];
  const float* b_q  = (const float*)d_in[4];
  const float* w_k  = (const float*)d_in[5];
  const float* b_k  = (const float*)d_in[6];
  const float* w_v  = (const float*)d_in[7];
  const float* b_v  = (const float*)d_in[8];
  const float* w_o  = (const float*)d_in[9];
  const float* b_o  = (const float*)d_in[10];
  const float* w_bd = (const float*)d_in[11];
  const float* b_bd = (const float*)d_in[12];
  const float* w_pr = (const float*)d_in[13];
  const float* b_pr = (const float*)d_in[14];
  float* out = (float*)d_out;
  float* ws = (float*)d_ws;

  const size_t M = (size_t)NB * NT;                      // 16384
  float* hbuf = ws;                                      // 4,194,304 f32
  unsigned short* hhi = (unsigned short*)(hbuf + M * NE);// 4,194,304 u16 each
  unsigned short* hlo = hhi + M * NE;
  unsigned short* qhi = hlo + M * NE;                    // q hi/lo ALSO used as x hi/lo
  unsigned short* qlo = qhi + M * NE;
  unsigned short* khi = qlo + M * NE;
  unsigned short* klo = khi + M * NE;
  unsigned short* wihi = klo + M * NE;                   // 65,536 u16 each
  unsigned short* wilo = wihi + 65536;
  unsigned short* wqkhi = wilo + 65536;                  // 131,072 u16 each
  unsigned short* wqklo = wqkhi + 131072;
  float* bqk    = (float*)(wqklo + 131072);              // 512
  float* vubuf  = bqk + 512;                             // 65,536 [B,H,T]
  float* spbuf  = vubuf + 65536;                         // 65,536 [B,T,H]
  float* uvbuf  = spbuf + 65536;                         // 1024
  float* consts = uvbuf + 1024;                          // 8
  float* psum   = consts + 8;                            // 16,384
  int*   pid    = (int*)(psum + 16384);                  // 16,384
  int*   counts = pid + 16384;                           // 64
  unsigned short* xhi = qhi;                             // alias (dead after mgemm<0>)
  unsigned short* xlo = qlo;

  prep_kernel<<<1, 256, 0, stream>>>(w_o, b_o, w_bd, b_bd, w_v, b_v, uvbuf, consts, psum);
  split_kernel<<<2048, 256, 0, stream>>>(x, xhi, xlo, (int)(M * NE / 4));
  split_kernel<<<64, 256, 0, stream>>>(w_in, wihi, wilo, 65536 / 4);
  wqk_kernel<<<512, 256, 0, stream>>>(w_q, w_k, b_q, b_k, wqkhi, wqklo, bqk);
  mgemm_kernel<0><<<dim3(128, 4), 256, 0, stream>>>(xhi, xlo, wihi, wilo, b_in,
      hbuf, hhi, hlo, nullptr, nullptr, nullptr, nullptr);
  mgemm_kernel<1><<<dim3(128, 8), 256, 0, stream>>>(hhi, hlo, wqkhi, wqklo, bqk,
      nullptr, nullptr, nullptr, qhi, qlo, khi, klo);
  vu_kernel<<<4096, 256, 0, stream>>>(hbuf, uvbuf, consts, vubuf);
  attn_kernel3<<<512, 512, 0, stream>>>(qhi, qlo, khi, klo, vubuf, spbuf);
  boundary_kernel<<<8, 256, 0, stream>>>(spbuf, consts, pid, counts);
  pool_kernel<<<128, 256, 0, stream>>>(hbuf, pid, psum);
  final_kernel<<<64, 256, 0, stream>>>(psum, counts, w_pr, b_pr, out);
}

// Round 4
// 194.082 us; speedup vs baseline: 2.4184x; 1.1382x over previous
//
#include <hip/hip_runtime.h>
#include <cstddef>

#define NB 8
#define NT 2048
#define NE 256
#define NH 4
#define ND 64
#define NP 8

typedef short bf16x8 __attribute__((ext_vector_type(8)));
typedef float f32x4 __attribute__((ext_vector_type(4)));

__device__ __forceinline__ unsigned short f2bf(float f) {
  unsigned u = __builtin_bit_cast(unsigned, f);
  u += 0x7fffu + ((u >> 16) & 1u);          // RNE
  return (unsigned short)(u >> 16);
}
__device__ __forceinline__ float bf2f(unsigned short h) {
  unsigned u = ((unsigned)h) << 16;
  return __builtin_bit_cast(float, u);
}

// ---------------- fused setup: x-split, w_in-split, w_qk-split(+q prescale), prep ------
// grid 2626 x 256:
//  [0,2048)    x hi/lo split (2 float4 each)
//  [2048,2560) w_q(*0.125)/w_k concat split + bias
//  [2560,2624) w_in split
//  2624        prep: uv, consts
//  2625        psum zero
__global__ __launch_bounds__(256) void setup_kernel(
    const float* __restrict__ x, const float* __restrict__ w_in,
    const float* __restrict__ w_q, const float* __restrict__ w_k,
    const float* __restrict__ b_q, const float* __restrict__ b_k,
    const float* __restrict__ w_o, const float* __restrict__ b_o,
    const float* __restrict__ w_bd, const float* __restrict__ b_bd,
    const float* __restrict__ w_v, const float* __restrict__ b_v,
    unsigned short* __restrict__ xhi, unsigned short* __restrict__ xlo,
    unsigned short* __restrict__ wihi, unsigned short* __restrict__ wilo,
    unsigned short* __restrict__ wqkhi, unsigned short* __restrict__ wqklo,
    float* __restrict__ bqk,
    float* __restrict__ uv, float* __restrict__ consts, float* __restrict__ psum)
{
  __shared__ float wbd_s[NE];
  __shared__ float u_s[NE];
  const int b = blockIdx.x, tid = threadIdx.x;
  if (b < 2048) {
    #pragma unroll
    for (int rep = 0; rep < 2; ++rep) {
      const int i = b * 256 + tid + rep * 524288;        // float4 index, n4 = 1048576
      const float4 v = *(const float4*)(x + (size_t)i * 4);
      const float vv[4] = {v.x, v.y, v.z, v.w};
      unsigned short h4[4], l4[4];
      #pragma unroll
      for (int j = 0; j < 4; ++j) {
        h4[j] = f2bf(vv[j]);
        l4[j] = f2bf(vv[j] - bf2f(h4[j]));
      }
      *(ushort2*)(xhi + (size_t)i * 4)     = make_ushort2(h4[0], h4[1]);
      *(ushort2*)(xhi + (size_t)i * 4 + 2) = make_ushort2(h4[2], h4[3]);
      *(ushort2*)(xlo + (size_t)i * 4)     = make_ushort2(l4[0], l4[1]);
      *(ushort2*)(xlo + (size_t)i * 4 + 2) = make_ushort2(l4[2], l4[3]);
    }
  } else if (b < 2560) {
    const int i = (b - 2048) * 256 + tid;                // [0,131072)
    const float v = (i < 65536) ? w_q[i] * 0.125f : w_k[i - 65536];
    const unsigned short h = f2bf(v);
    wqkhi[i] = h;
    wqklo[i] = f2bf(v - bf2f(h));
    if (i < 512) bqk[i] = (i < 256) ? b_q[i] * 0.125f : b_k[i - 256];
  } else if (b < 2624) {
    const int i = (b - 2560) * 256 + tid;                // float4 index, [0,16384)
    const float4 v = *(const float4*)(w_in + (size_t)i * 4);
    const float vv[4] = {v.x, v.y, v.z, v.w};
    unsigned short h4[4], l4[4];
    #pragma unroll
    for (int j = 0; j < 4; ++j) {
      h4[j] = f2bf(vv[j]);
      l4[j] = f2bf(vv[j] - bf2f(h4[j]));
    }
    *(ushort2*)(wihi + (size_t)i * 4)     = make_ushort2(h4[0], h4[1]);
    *(ushort2*)(wihi + (size_t)i * 4 + 2) = make_ushort2(h4[2], h4[3]);
    *(ushort2*)(wilo + (size_t)i * 4)     = make_ushort2(l4[0], l4[1]);
    *(ushort2*)(wilo + (size_t)i * 4 + 2) = make_ushort2(l4[2], l4[3]);
  } else if (b == 2624) {
    wbd_s[tid] = w_bd[tid];
    __syncthreads();
    float a = 0.f;
    for (int j = 0; j < NE; ++j) a = fmaf(wbd_s[j], w_o[j * NE + tid], a);
    u_s[tid] = a;
    __syncthreads();
    #pragma unroll
    for (int hh = 0; hh < NH; ++hh) {
      float a2 = 0.f;
      for (int d = 0; d < ND; ++d)
        a2 = fmaf(u_s[hh * ND + d], w_v[(size_t)(hh * ND + d) * NE + tid], a2);
      uv[hh * NE + tid] = a2;
    }
    if (tid == 0) {
      float cc = 0.f;
      for (int j = 0; j < NE; ++j) cc = fmaf(wbd_s[j], b_o[j], cc);
      consts[0] = cc + b_bd[0];
    }
    if (tid >= 4 && tid < 8) {
      const int hh = tid - 4;
      float cv = 0.f;
      for (int d = 0; d < ND; ++d) cv = fmaf(u_s[hh * ND + d], b_v[hh * ND + d], cv);
      consts[1 + hh] = cv;
    }
  } else {
    for (int i = tid; i < NB * NP * NE; i += 256) psum[i] = 0.f;
  }
}

// ---------------- compensated bf16 MFMA GEMM: C = (Ahi+Alo)(Whi+Wlo)^T + bias ----------
// K=256. Block 256 thr = 4 waves; tile 128 rows x 64 cols; wave = 32 rows.
// MODE 0: Cf f32 [M][256] + Chi/Clo bf16 [M][256].  MODE 1: q/k head-split hi/lo.
template <int MODE>
__global__ __launch_bounds__(256) void mgemm_kernel(
    const unsigned short* __restrict__ Ahi, const unsigned short* __restrict__ Alo,
    const unsigned short* __restrict__ Whi, const unsigned short* __restrict__ Wlo,
    const float* __restrict__ bias,
    float* __restrict__ Cf, unsigned short* __restrict__ Chi, unsigned short* __restrict__ Clo,
    unsigned short* __restrict__ Qhi, unsigned short* __restrict__ Qlo,
    unsigned short* __restrict__ Khi, unsigned short* __restrict__ Klo)
{
  const int tid = threadIdx.x;
  const int wave = tid >> 6, lane = tid & 63;
  const int lr = lane & 15, lg = lane >> 4;
  const int m0 = blockIdx.x * 128, n0 = blockIdx.y * 64;
  const int wrow0 = m0 + wave * 32;
  f32x4 acc[2][4];
  #pragma unroll
  for (int s = 0; s < 2; ++s)
    #pragma unroll
    for (int ns = 0; ns < 4; ++ns) acc[s][ns] = (f32x4){0.f, 0.f, 0.f, 0.f};

  #pragma unroll 2
  for (int k0 = 0; k0 < 256; k0 += 32) {
    bf16x8 a[2][2], bf[4][2];
    #pragma unroll
    for (int s = 0; s < 2; ++s) {
      const size_t off = (size_t)(wrow0 + s * 16 + lr) * 256 + k0 + lg * 8;
      a[s][0] = *(const bf16x8*)(Ahi + off);
      a[s][1] = *(const bf16x8*)(Alo + off);
    }
    #pragma unroll
    for (int ns = 0; ns < 4; ++ns) {
      const size_t off = (size_t)(n0 + ns * 16 + lr) * 256 + k0 + lg * 8;
      bf[ns][0] = *(const bf16x8*)(Whi + off);
      bf[ns][1] = *(const bf16x8*)(Wlo + off);
    }
    #pragma unroll
    for (int s = 0; s < 2; ++s)
      #pragma unroll
      for (int ns = 0; ns < 4; ++ns) {
        acc[s][ns] = __builtin_amdgcn_mfma_f32_16x16x32_bf16(a[s][0], bf[ns][0], acc[s][ns], 0, 0, 0);
        acc[s][ns] = __builtin_amdgcn_mfma_f32_16x16x32_bf16(a[s][0], bf[ns][1], acc[s][ns], 0, 0, 0);
        acc[s][ns] = __builtin_amdgcn_mfma_f32_16x16x32_bf16(a[s][1], bf[ns][0], acc[s][ns], 0, 0, 0);
      }
  }
  // epilogue: D layout col=lane&15, row=4*(lane>>4)+reg
  #pragma unroll
  for (int s = 0; s < 2; ++s)
    #pragma unroll
    for (int ns = 0; ns < 4; ++ns)
      #pragma unroll
      for (int reg = 0; reg < 4; ++reg) {
        const int row = wrow0 + s * 16 + lg * 4 + reg;
        const int col = n0 + ns * 16 + lr;
        const float v = acc[s][ns][reg] + bias[col];
        if (MODE == 0) {
          const size_t idx = (size_t)row * 256 + col;
          Cf[idx] = v;
          const unsigned short hb = f2bf(v);
          Chi[idx] = hb;
          Clo[idx] = f2bf(v - bf2f(hb));
        } else {
          const int c = col & 255;
          const int head = c >> 6, d = c & 63;
          const int b = row >> 11, t = row & 2047;
          const size_t idx = (((size_t)(b * NH + head)) * NT + t) * ND + d;
          const unsigned short hb = f2bf(v);
          if (col < 256) { Qhi[idx] = hb; Qlo[idx] = f2bf(v - bf2f(hb)); }
          else           { Khi[idx] = hb; Klo[idx] = f2bf(v - bf2f(hb)); }
        }
      }
}

// ---------------- vu[b,h,t] = h_row . uv_h + cv_h (one wave per token) ----------------
__global__ __launch_bounds__(256) void vu_kernel(
    const float* __restrict__ h, const float* __restrict__ uv,
    const float* __restrict__ consts, float* __restrict__ vuout)
{
  __shared__ float uv_s[NH][NE];
  const int tid = threadIdx.x;
  #pragma unroll
  for (int i = 0; i < 4; ++i) { const int idx = i * 256 + tid; uv_s[idx >> 8][idx & 255] = uv[idx]; }
  __syncthreads();
  const int wave = tid >> 6, lane = tid & 63;
  const int token = blockIdx.x * 4 + wave;            // = b*NT + t
  const float4 hv = *(const float4*)(h + (size_t)token * NE + lane * 4);
  const int b = token >> 11, t = token & 2047;
  #pragma unroll
  for (int hh = 0; hh < NH; ++hh) {
    float p = hv.x * uv_s[hh][lane * 4 + 0] + hv.y * uv_s[hh][lane * 4 + 1]
            + hv.z * uv_s[hh][lane * 4 + 2] + hv.w * uv_s[hh][lane * 4 + 3];
    #pragma unroll
    for (int off = 32; off > 0; off >>= 1) p += __shfl_down(p, off);
    if (lane == 0) vuout[((size_t)(b * NH + hh)) * NT + t] = p + consts[1 + hh];
  }
}

// ---------------- attention v4: no-max softmax, 32-row waves, split-K x2 ---------------
// partial (l, sv) per (bh, row, kh); q pre-scaled by 0.125 in weights.
// Block = 512 thr / 8 waves; wave = 32 q-rows; block = 256 q-rows, 1024 k-rows (16 tiles).
__global__ __launch_bounds__(512) void attn_kernel4(
    const unsigned short* __restrict__ qhi, const unsigned short* __restrict__ qlo,
    const unsigned short* __restrict__ khi, const unsigned short* __restrict__ klo,
    const float* __restrict__ vu, float2* __restrict__ part2)
{
  __shared__ __align__(16) char kbuf[2][16384];   // [buf][hi 8KB | lo 8KB], XOR-swizzled
  __shared__ float vu_s[1024];
  const int tid = threadIdx.x;
  const int wave = tid >> 6, lane = tid & 63;
  const int lr = lane & 15, lg = lane >> 4;
  // XCD-aware: bid&7 -> XCD gets 4 contiguous bh
  const int bid = blockIdx.x;                     // 0..511
  const int g = bid >> 3;                         // 0..63
  const int bh = (bid & 7) * 4 + (g >> 4);
  const int qt = (g & 15) >> 1, kh = g & 1;
  const size_t base = (size_t)bh * NT * ND;
  const int qrow0 = qt * 256 + wave * 32;
  const int krow0 = kh * 1024;

  *(float2*)&vu_s[tid * 2] = *(const float2*)(vu + (size_t)bh * NT + krow0 + tid * 2);

  // Q fragments in regs: [m-subtile][d-slice][hi/lo]
  bf16x8 qf[2][2][2];
  #pragma unroll
  for (int s = 0; s < 2; ++s)
    #pragma unroll
    for (int ds = 0; ds < 2; ++ds) {
      const size_t off = base + (size_t)(qrow0 + s * 16 + lr) * ND + ds * 32 + lg * 8;
      qf[s][ds][0] = *(const bf16x8*)(qhi + off);
      qf[s][ds][1] = *(const bf16x8*)(qlo + off);
    }

  // staging / read offsets with XOR swizzle (same involution both sides)
  const int o = tid * 16;
  const int so = o ^ (((o >> 7) & 7) << 4);
  int ro0[4], ro1[4];
  #pragma unroll
  for (int ns = 0; ns < 4; ++ns) {
    const int r = ns * 16 + lr;
    const int sw = (r & 7) << 4;
    const int ob = r * 128 + lg * 16;
    ro0[ns] = ob ^ sw;
    ro1[ns] = (ob + 64) ^ sw;
  }
  const unsigned short* ksrc_h = khi + base + (size_t)krow0 * ND;
  const unsigned short* ksrc_l = klo + base + (size_t)krow0 * ND;
  bf16x8 nh = *(const bf16x8*)(ksrc_h + tid * 8);
  bf16x8 nl = *(const bf16x8*)(ksrc_l + tid * 8);

  float l[8], sv[8];
  #pragma unroll
  for (int i = 0; i < 8; ++i) { l[i] = 0.f; sv[i] = 0.f; }

  #pragma unroll 2
  for (int kt = 0; kt < 16; ++kt) {
    char* kb = (char*)kbuf[kt & 1];
    *(bf16x8*)&kb[so] = nh;                       // write staged tile
    *(bf16x8*)&kb[8192 + so] = nl;
    __syncthreads();                              // single barrier per tile
    if (kt < 15) {                                // prefetch next tile (overlaps compute)
      nh = *(const bf16x8*)(ksrc_h + (size_t)(kt + 1) * 4096 + tid * 8);
      nl = *(const bf16x8*)(ksrc_l + (size_t)(kt + 1) * 4096 + tid * 8);
    }
    f32x4 acc[2][4];
    float vuv[4];
    #pragma unroll
    for (int ns = 0; ns < 4; ++ns) {
      const bf16x8 kh0 = *(const bf16x8*)(kb + ro0[ns]);
      const bf16x8 kh1 = *(const bf16x8*)(kb + ro1[ns]);
      const bf16x8 kl0 = *(const bf16x8*)(kb + 8192 + ro0[ns]);
      const bf16x8 kl1 = *(const bf16x8*)(kb + 8192 + ro1[ns]);
      vuv[ns] = vu_s[kt * 64 + ns * 16 + lr];
      #pragma unroll
      for (int s = 0; s < 2; ++s) {
        acc[s][ns] = (f32x4){0.f, 0.f, 0.f, 0.f};
        acc[s][ns] = __builtin_amdgcn_mfma_f32_16x16x32_bf16(qf[s][0][0], kh0, acc[s][ns], 0, 0, 0);
        acc[s][ns] = __builtin_amdgcn_mfma_f32_16x16x32_bf16(qf[s][0][0], kl0, acc[s][ns], 0, 0, 0);
        acc[s][ns] = __builtin_amdgcn_mfma_f32_16x16x32_bf16(qf[s][0][1], kh0, acc[s][ns], 0, 0, 0);
        acc[s][ns] = __builtin_amdgcn_mfma_f32_16x16x32_bf16(qf[s][1][0], kh1, acc[s][ns], 0, 0, 0);
        acc[s][ns] = __builtin_amdgcn_mfma_f32_16x16x32_bf16(qf[s][1][0], kl1, acc[s][ns], 0, 0, 0);
        acc[s][ns] = __builtin_amdgcn_mfma_f32_16x16x32_bf16(qf[s][1][1], kh1, acc[s][ns], 0, 0, 0);
      }
    }
    // no-max softmax accumulation (scores pre-scaled by 0.125 via q)
    #pragma unroll
    for (int s = 0; s < 2; ++s)
      #pragma unroll
      for (int reg = 0; reg < 4; ++reg) {
        const int ri = s * 4 + reg;
        #pragma unroll
        for (int ns = 0; ns < 4; ++ns) {
          const float e = __expf(acc[s][ns][reg]);
          l[ri] += e;
          sv[ri] = fmaf(e, vuv[ns], sv[ri]);
        }
      }
  }
  // reduce partial l/sv across the 16-lane column group
  #pragma unroll
  for (int ri = 0; ri < 8; ++ri) {
    #pragma unroll
    for (int off = 1; off < 16; off <<= 1) {
      l[ri]  += __shfl_xor(l[ri],  off, 16);
      sv[ri] += __shfl_xor(sv[ri], off, 16);
    }
  }
  if (lr == 0) {
    #pragma unroll
    for (int s = 0; s < 2; ++s)
      #pragma unroll
      for (int reg = 0; reg < 4; ++reg) {
        const int row = qrow0 + s * 16 + lg * 4 + reg;
        part2[((size_t)bh * NT + row) * 2 + kh] = make_float2(l[s * 4 + reg], sv[s * 4 + reg]);
      }
  }
}

// ---------------- boundary: combine split-K, sigmoid, cumsum, pid, counts --------------
__global__ __launch_bounds__(256) void boundary_kernel(
    const float4* __restrict__ part4, const float* __restrict__ consts,
    int* __restrict__ pid, int* __restrict__ counts)
{
  const int b = blockIdx.x, tid = threadIdx.x;
  __shared__ float partial[256];
  __shared__ int cnt_s[8];
  const float c = consts[0];
  float v[8];
  float run = 0.f;
  #pragma unroll
  for (int i = 0; i < 8; ++i) {
    const int t = tid * 8 + i;
    float logit = c;
    #pragma unroll
    for (int hh = 0; hh < NH; ++hh) {
      const float4 p = part4[(size_t)(b * NH + hh) * NT + t];   // {l0, sv0, l1, sv1}
      logit += (p.y + p.w) / (p.x + p.z);
    }
    const float bs = 1.f / (1.f + expf(-logit));
    run += bs;
    v[i] = run;
  }
  float x = run;
  partial[tid] = x;
  __syncthreads();
  for (int off = 1; off < 256; off <<= 1) {
    const float y = (tid >= off) ? partial[tid - off] : 0.f;
    __syncthreads();
    x += y;
    partial[tid] = x;
    __syncthreads();
  }
  const float total = partial[255];
  if (tid < 8) cnt_s[tid] = 0;
  __syncthreads();
  const float denom = fmaxf(total, 1e-6f);
  const float excl = x - run;
  #pragma unroll
  for (int i = 0; i < 8; ++i) {
    const float norm = (excl + v[i]) / denom;
    int pp = (int)(norm * 8.f);
    pp = pp > 7 ? 7 : pp;
    pid[b * NT + tid * 8 + i] = pp;
    atomicAdd(&cnt_s[pp], 1);
  }
  __syncthreads();
  if (tid < 8) counts[b * 8 + tid] = cnt_s[tid];
}

// ---------------- pool h into patch sums (branchless 8-way select) --------------------
__global__ __launch_bounds__(256) void pool_kernel(
    const float* __restrict__ h, const int* __restrict__ pid, float* __restrict__ psum)
{
  const int b = blockIdx.x >> 4, chunk = blockIdx.x & 15;
  const int tid = threadIdx.x;
  __shared__ int pid_s[128];
  const int t0 = chunk * 128;
  if (tid < 128) pid_s[tid] = pid[b * NT + t0 + tid];
  __syncthreads();
  float acc[8] = {};
  for (int tok = 0; tok < 128; ++tok) {
    const float val = h[((size_t)b * NT + t0 + tok) * NE + tid];
    const int p = pid_s[tok];
    #pragma unroll
    for (int pp = 0; pp < 8; ++pp) acc[pp] += (p == pp) ? val : 0.f;
  }
  #pragma unroll
  for (int pp = 0; pp < 8; ++pp)
    atomicAdd(&psum[((size_t)b * NP + pp) * NE + tid], acc[pp]);
}

// ---------------- final: out = (psum/count) @ w_pr^T + b_pr --------------------------
__global__ __launch_bounds__(256) void final_kernel(
    const float* __restrict__ psum, const int* __restrict__ counts,
    const float* __restrict__ w_pr, const float* __restrict__ b_pr, float* __restrict__ out)
{
  const int bp = blockIdx.x;
  const int tid = threadIdx.x;
  __shared__ float pe[NE];
  const float cnt = fmaxf((float)counts[bp], 1.f);
  pe[tid] = psum[(size_t)bp * NE + tid] / cnt;
  __syncthreads();
  float acc = 0.f;
  for (int e = 0; e < NE; ++e) acc = fmaf(pe[e], w_pr[(size_t)tid * NE + e], acc);
  out[(size_t)bp * NE + tid] = acc + b_pr[tid];
}

extern "C" void kernel_launch(void* const* d_in, const int* in_sizes, int n_in,
                              void* d_out, int out_size, void* d_ws, size_t ws_size,
                              hipStream_t stream) {
  (void)in_sizes; (void)n_in; (void)out_size; (void)ws_size;
  const float* x    = (const float*)d_in[0];
  const float* w_in = (const float*)d_in[1];
  const float* b_in = (const float*)d_in[2];
  const float* w_q  = (const float*)d_in[3];
  const float* b_q  = (const float*)d_in[4];
  const float* w_k  = (const float*)d_in[5];
  const float* b_k  = (const float*)d_in[6];
  const float* w_v  = (const float*)d_in[7];
  const float* b_v  = (const float*)d_in[8];
  const float* w_o  = (const float*)d_in[9];
  const float* b_o  = (const float*)d_in[10];
  const float* w_bd = (const float*)d_in[11];
  const float* b_bd = (const float*)d_in[12];
  const float* w_pr = (const float*)d_in[13];
  const float* b_pr = (const float*)d_in[14];
  float* out = (float*)d_out;
  float* ws = (float*)d_ws;

  const size_t M = (size_t)NB * NT;                      // 16384
  float* hbuf = ws;                                      // 4,194,304 f32
  unsigned short* hhi = (unsigned short*)(hbuf + M * NE);// 4,194,304 u16 each
  unsigned short* hlo = hhi + M * NE;
  unsigned short* qhi = hlo + M * NE;                    // also x hi/lo (dead after mgemm<0>)
  unsigned short* qlo = qhi + M * NE;
  unsigned short* khi = qlo + M * NE;
  unsigned short* klo = khi + M * NE;
  unsigned short* wihi = klo + M * NE;                   // 65,536 u16 each
  unsigned short* wilo = wihi + 65536;
  unsigned short* wqkhi = wilo + 65536;                  // 131,072 u16 each
  unsigned short* wqklo = wqkhi + 131072;
  float* bqk    = (float*)(wqklo + 131072);              // 512
  float* vubuf  = bqk + 512;                             // 65,536 [B,H,T]
  float* partbuf= vubuf + 65536;                         // 262,144 [bh][t][kh][{l,sv}]
  float* uvbuf  = partbuf + 262144;                      // 1024
  float* consts = uvbuf + 1024;                          // 8
  float* psum   = consts + 8;                            // 16,384
  int*   pid    = (int*)(psum + 16384);                  // 16,384
  int*   counts = pid + 16384;                           // 64
  unsigned short* xhi = qhi;                             // alias
  unsigned short* xlo = qlo;

  setup_kernel<<<2626, 256, 0, stream>>>(x, w_in, w_q, w_k, b_q, b_k, w_o, b_o,
      w_bd, b_bd, w_v, b_v, xhi, xlo, wihi, wilo, wqkhi, wqklo, bqk,
      uvbuf, consts, psum);
  mgemm_kernel<0><<<dim3(128, 4), 256, 0, stream>>>(xhi, xlo, wihi, wilo, b_in,
      hbuf, hhi, hlo, nullptr, nullptr, nullptr, nullptr);
  mgemm_kernel<1><<<dim3(128, 8), 256, 0, stream>>>(hhi, hlo, wqkhi, wqklo, bqk,
      nullptr, nullptr, nullptr, qhi, qlo, khi, klo);
  vu_kernel<<<4096, 256, 0, stream>>>(hbuf, uvbuf, consts, vubuf);
  attn_kernel4<<<512, 512, 0, stream>>>(qhi, qlo, khi, klo, vubuf, (float2*)partbuf);
  boundary_kernel<<<8, 256, 0, stream>>>((const float4*)partbuf, consts, pid, counts);
  pool_kernel<<<128, 256, 0, stream>>>(hbuf, pid, psum);
  final_kernel<<<64, 256, 0, stream>>>(psum, counts, w_pr, b_pr, out);
}